// Round 5
// baseline (367.551 us; speedup 1.0000x reference)
//
#include <hip/hip_runtime.h>

// ---------------------------------------------------------------------------
// GraphEncoder round 19: wgemm parallelism fix. R17 falsified the LDS/VGPR
// occupancy theory (occupancy pinned at ~16% regardless); the real limiter is
// block count: 782 long-lived blocks over 256 CUs = ~3/CU, no oversubscription.
// wgemm blocks shrink to 128 threads / 2 waves / 64 rows -> 1564 blocks
// (6.1/CU available vs 5 LDS slots = real pipelining), MLP GEMMs get 2x
// blocks too. Epilogue's dependent loads (residual rows, dinv) prefetched in
// the prologue (+18 VGPR, <=128). R18 swizzled B-stage + NT=2 retained.
// ---------------------------------------------------------------------------

typedef __attribute__((ext_vector_type(8))) short short8;
typedef __attribute__((ext_vector_type(4))) float f32x4;
typedef __attribute__((ext_vector_type(2))) float f32x2;

__device__ __forceinline__ float bf2f(unsigned short s) {
    union { unsigned u; float f; } v;
    v.u = ((unsigned)s) << 16;
    return v.f;
}
__device__ __forceinline__ unsigned short f2bf(float f) {
    union { float f; unsigned u; } v;
    v.f = f;
    unsigned r = (v.u + 0x7FFFu + ((v.u >> 16) & 1u)) >> 16;
    return (unsigned short)r;
}
__device__ __forceinline__ unsigned pk2bf(float lo, float hi) {
    return (unsigned)f2bf(lo) | ((unsigned)f2bf(hi) << 16);
}
__device__ __forceinline__ unsigned short u4c(ushort4 v, int p) {
    return p == 0 ? v.x : p == 1 ? v.y : p == 2 ? v.z : v.w;
}

// accumulate 8 fp8 values (two packed dwords) into acc[0..8)
__device__ __forceinline__ void acc8_fp8(unsigned int lo, unsigned int hi, float* acc) {
    f32x2 p0 = __builtin_amdgcn_cvt_pk_f32_fp8(lo, false);
    f32x2 p1 = __builtin_amdgcn_cvt_pk_f32_fp8(lo, true);
    f32x2 p2 = __builtin_amdgcn_cvt_pk_f32_fp8(hi, false);
    f32x2 p3 = __builtin_amdgcn_cvt_pk_f32_fp8(hi, true);
    acc[0] += p0[0]; acc[1] += p0[1]; acc[2] += p1[0]; acc[3] += p1[1];
    acc[4] += p2[0]; acc[5] += p2[1]; acc[6] += p3[0]; acc[7] += p3[1];
}

// ---------------------------- CSR build ------------------------------------

__global__ void count_kernel(const int* __restrict__ dst, int E, int* __restrict__ cnt,
                             int* __restrict__ rank) {
    int e = blockIdx.x * blockDim.x + threadIdx.x;
    if (e < E) rank[e] = atomicAdd(&cnt[dst[e]], 1);
}

__global__ void scanA(const int* __restrict__ cnt, int n, int* __restrict__ bsum,
                      float* __restrict__ dinv) {
    int tid = threadIdx.x, lane = tid & 63, w = tid >> 6;
    int i = blockIdx.x * 512 + tid;
    int v = (i < n) ? cnt[i] : 0;
    if (i < n) dinv[i] = rsqrtf((float)v + 1.0f);
    int s = v;
    #pragma unroll
    for (int off = 1; off < 64; off <<= 1) s += __shfl_xor(s, off);
    __shared__ int ws[8];
    if (lane == 0) ws[w] = s;
    __syncthreads();
    if (tid == 0) {
        int t = 0;
        #pragma unroll
        for (int j = 0; j < 8; j++) t += ws[j];
        bsum[blockIdx.x] = t;
    }
}

__global__ void scanC(const int* __restrict__ cnt, int n, const int* __restrict__ bsum,
                      int E, int* __restrict__ row_ptr) {
    int tid = threadIdx.x, lane = tid & 63, w = tid >> 6;
    int i = blockIdx.x * 512 + tid;
    __shared__ int s_boff;
    if (tid < 64) {
        int acc = 0;
        for (int b = tid; b < blockIdx.x; b += 64) acc += bsum[b];
        #pragma unroll
        for (int off = 1; off < 64; off <<= 1) acc += __shfl_xor(acc, off);
        if (tid == 0) s_boff = acc;
    }
    int v = (i < n) ? cnt[i] : 0;
    int incl = v;
    #pragma unroll
    for (int off = 1; off < 64; off <<= 1) {
        int t = __shfl_up(incl, off);
        if (lane >= off) incl += t;
    }
    __shared__ int ws[8];
    if (lane == 63) ws[w] = incl;
    __syncthreads();
    int woff = 0;
    for (int j = 0; j < w; j++) woff += ws[j];
    if (i < n) row_ptr[i] = s_boff + woff + incl - v;
    if (blockIdx.x == 0 && tid == 0) row_ptr[n] = E;
}

// ---------------------------- fused scatter + conversions ------------------

__global__ void convert_all(const int* __restrict__ src, const int* __restrict__ dst,
                            const int* __restrict__ row_ptr, const int* __restrict__ rank,
                            int* __restrict__ csr, int E,
                            const float* __restrict__ x, const float* __restrict__ dinv,
                            unsigned char* __restrict__ xf8, int n4,
                            const float* __restrict__ W1, const float* __restrict__ W2,
                            const float* __restrict__ W3, const float* __restrict__ P1,
                            const float* __restrict__ P2,
                            unsigned short* __restrict__ Wt1, unsigned short* __restrict__ Wt2,
                            unsigned short* __restrict__ Wt3, unsigned short* __restrict__ Pt1,
                            unsigned short* __restrict__ Pt2,
                            int F_IN, int H, int D,
                            unsigned char* __restrict__ zx,
                            unsigned char* __restrict__ z1,
                            unsigned char* __restrict__ z2) {
    int gidx = blockIdx.x * blockDim.x + threadIdx.x;
    if (gidx < E) {
        csr[row_ptr[dst[gidx]] + rank[gidx]] = src[gidx];
        return;
    }
    int idx = gidx - E;
    if (idx < n4) {
        float di = dinv[idx >> 5];
        float4 v = ((const float4*)x)[idx];
        unsigned int p = 0;
        p = __builtin_amdgcn_cvt_pk_fp8_f32(di * v.x, di * v.y, p, false);
        p = __builtin_amdgcn_cvt_pk_fp8_f32(di * v.z, di * v.w, p, true);
        ((unsigned int*)xf8)[idx] = p;
        return;
    }
    int t = idx - n4;
    int n1 = F_IN * H, n2 = H * H, n5 = H * D;
    const float* W; unsigned short* O; int N;
    if (t < n1)              { W = W1; O = Wt1; N = H; }
    else if ((t -= n1) < n2) { W = W2; O = Wt2; N = H; }
    else if ((t -= n2) < n2) { W = W3; O = Wt3; N = H; }
    else if ((t -= n2) < n2) { W = P1; O = Pt1; N = H; }
    else if ((t -= n2) < n5) { W = P2; O = Pt2; N = D; }
    else {
        t -= n5;
        if (t < 128) zx[t] = 0;
        else if (t < 384) z1[t - 128] = 0;
        else if (t < 640) z2[t - 384] = 0;
        return;
    }
    int k = t / N, n = t - k * N;
    int K = (W == W1) ? F_IN : H;
    O[(size_t)n * K + k] = f2bf(W[t]);
}

// ---------------------------- aggregation (fp8 gathers, R14 shape) ---------

__launch_bounds__(256)
__global__ void aggregate256(const unsigned char* __restrict__ hf8,
                             const int* __restrict__ row_ptr,
                             const int* __restrict__ csr,
                             unsigned short* __restrict__ out, int n, int zrow) {
    int node = blockIdx.x * 4 + (threadIdx.x >> 6);
    int lane = threadIdx.x & 63;
    if (node >= n) return;
    int half = lane >> 5;          // which edge of the pair
    int cl = lane & 31;            // 8-col chunk
    float acc[8] = {0, 0, 0, 0, 0, 0, 0, 0};
    if (half == 0) {
        uint2 sv = *(const uint2*)(hf8 + (size_t)node * 256 + cl * 8);
        acc8_fp8(sv.x, sv.y, acc);
    }
    int beg = row_ptr[node], end = row_ptr[node + 1];
    for (int base = beg; base < end; base += 64) {
        int k = base + lane;
        int mi = (k < end) ? csr[k] : zrow;
        int cnt = min(64, end - base);
        for (int j = 0; j < cnt; j += 16) {
            int idx[8]; uint2 vv[8];
            #pragma unroll
            for (int u = 0; u < 8; u++) idx[u] = __shfl(mi, j + 2 * u + half);
            #pragma unroll
            for (int u = 0; u < 8; u++) vv[u] = *(const uint2*)(hf8 + (size_t)idx[u] * 256 + cl * 8);
            #pragma unroll
            for (int u = 0; u < 8; u++) acc8_fp8(vv[u].x, vv[u].y, acc);
        }
    }
    #pragma unroll
    for (int c = 0; c < 8; c++) acc[c] += __shfl_xor(acc[c], 32);
    if (half == 0) {
        short8 o;
        #pragma unroll
        for (int c = 0; c < 8; c++) o[c] = (short)f2bf(acc[c]);
        *(short8*)(out + (size_t)node * 256 + cl * 8) = o;
    }
}

__launch_bounds__(256)
__global__ void aggregate128(const unsigned char* __restrict__ hf8,
                             const int* __restrict__ row_ptr,
                             const int* __restrict__ csr,
                             unsigned short* __restrict__ out, int n, int zrow) {
    int node = blockIdx.x * 4 + (threadIdx.x >> 6);
    int lane = threadIdx.x & 63;
    if (node >= n) return;
    int qtr = lane >> 4;           // which edge of the quad
    int cl = lane & 15;            // 8-col chunk
    float acc[8] = {0, 0, 0, 0, 0, 0, 0, 0};
    if (qtr == 0) {
        uint2 sv = *(const uint2*)(hf8 + (size_t)node * 128 + cl * 8);
        acc8_fp8(sv.x, sv.y, acc);
    }
    int beg = row_ptr[node], end = row_ptr[node + 1];
    for (int base = beg; base < end; base += 64) {
        int k = base + lane;
        int mi = (k < end) ? csr[k] : zrow;
        int cnt = min(64, end - base);
        for (int j = 0; j < cnt; j += 32) {
            int idx[8]; uint2 vv[8];
            #pragma unroll
            for (int u = 0; u < 8; u++) idx[u] = __shfl(mi, j + 4 * u + qtr);
            #pragma unroll
            for (int u = 0; u < 8; u++) vv[u] = *(const uint2*)(hf8 + (size_t)idx[u] * 128 + cl * 8);
            #pragma unroll
            for (int u = 0; u < 8; u++) acc8_fp8(vv[u].x, vv[u].y, acc);
        }
    }
    #pragma unroll
    for (int c = 0; c < 8; c++) {
        acc[c] += __shfl_xor(acc[c], 16);
        acc[c] += __shfl_xor(acc[c], 32);
    }
    if (qtr == 0) {
        short8 o;
        #pragma unroll
        for (int c = 0; c < 8; c++) o[c] = (short)f2bf(acc[c]);
        *(short8*)(out + (size_t)node * 128 + cl * 8) = o;
    }
}

// ---------------------------- wgemm ----------------------------------------
// C = epi(A[M,K] @ Bt[N,K]^T). 128-thr blocks = 2 waves x 32 rows (64 rows).
// A frags in registers; residual rows + dinv prefetched in the prologue;
// per 64-col tile B staged to LDS with XOR-swizzled 16B chunk slots
// (slot = ch ^ (row&7); row stride = K shorts) -> conflict-free ds_read_b128.
// Swapped-operand MFMA -> C^T frags; register-only butterfly transpose
// epilogue (R16). NT compile-time tiles per block share one A-frag load.
// SCALE: 0 plain; 1: v=relu(di*acc+b)[+res/di], store di*v; 2: ...store v.
// FP8O: also store v as fp8 shadow (gather copy for the next aggregate).

template<int K, int NT, int RELU, int RES, int OUTF32, int SCALE, int FP8O>
__launch_bounds__(128)
__global__ void wgemm(const unsigned short* __restrict__ A,
                      const unsigned short* __restrict__ Bt,
                      const float* __restrict__ bias,
                      const unsigned short* __restrict__ residual,
                      const float* __restrict__ dinv,
                      void* __restrict__ Cout,
                      unsigned char* __restrict__ f8out,
                      int M, int N) {
    constexpr int KK = K / 32;
    constexpr int CPR = K / 8;
    __shared__ __align__(16) unsigned short Bs[64 * K];

    int tid = threadIdx.x;
    int wave = tid >> 6, lane = tid & 63;
    int r = lane & 15, q = lane >> 4;
    int mr = blockIdx.y * 64 + wave * 32;
    int nbase = blockIdx.x * NT * 64;

    short8 a[2][KK];
    #pragma unroll
    for (int mi = 0; mi < 2; mi++) {
        int arow = mr + mi * 16 + r;
        bool aok = arow < M;
        const unsigned short* ap = A + (size_t)(aok ? arow : 0) * K;
        #pragma unroll
        for (int kk = 0; kk < KK; kk++) {
            short8 v = *(const short8*)(ap + kk * 32 + q * 8);
            if (!aok) v = (short8){0, 0, 0, 0, 0, 0, 0, 0};
            a[mi][kk] = v;
        }
    }

    // prologue prefetch: residual rows + dinv (hides the epilogue round-trip)
    ushort4 rv[NT][2][4];
    float dvi[2];
    #pragma unroll
    for (int mi = 0; mi < 2; mi++) {
        int m = mr + mi * 16 + r;
        bool ok = m < M;
        if (SCALE) dvi[mi] = dinv[ok ? m : 0];
        if (RES) {
            const unsigned short* rp = residual + (size_t)(ok ? m : 0) * N + q * 4;
            #pragma unroll
            for (int t = 0; t < NT; t++)
                #pragma unroll
                for (int j = 0; j < 4; j++)
                    rv[t][mi][j] = *(const ushort4*)(rp + nbase + t * 64 + j * 16);
        }
    }

    #pragma unroll
    for (int t = 0; t < NT; t++) {
        int n0 = nbase + t * 64;
        if (t > 0) __syncthreads();
        #pragma unroll
        for (int pass = 0; pass < 64 * CPR / 128; pass++) {
            int f = pass * 128 + tid;
            int row = f / CPR, ch = f % CPR;
            *(short8*)&Bs[row * K + (ch ^ (row & 7)) * 8] =
                *(const short8*)(Bt + (size_t)(n0 + row) * K + ch * 8);
        }
        __syncthreads();

        f32x4 acc[2][4];
        #pragma unroll
        for (int mi = 0; mi < 2; mi++)
            #pragma unroll
            for (int j = 0; j < 4; j++) acc[mi][j] = (f32x4){0.f, 0.f, 0.f, 0.f};

        #pragma unroll
        for (int kk = 0; kk < KK; kk++) {
            short8 b[4];
            #pragma unroll
            for (int j = 0; j < 4; j++)
                b[j] = *(short8*)&Bs[(j * 16 + r) * K + ((kk * 4 + q) ^ (r & 7)) * 8];
            #pragma unroll
            for (int mi = 0; mi < 2; mi++)
                #pragma unroll
                for (int j = 0; j < 4; j++)
                    acc[mi][j] = __builtin_amdgcn_mfma_f32_16x16x32_bf16(b[j], a[mi][kk], acc[mi][j], 0, 0, 0);
        }

        // --- epilogue (register-only) ---
        // lane(q,r), reg p of acc[mi][j]: C[m = mr+mi*16+r][n = n0+j*16+q*4+p]
        f32x4 bq[4];
        #pragma unroll
        for (int j = 0; j < 4; j++)
            bq[j] = *(const f32x4*)&bias[n0 + j * 16 + q * 4];

        #pragma unroll
        for (int mi = 0; mi < 2; mi++) {
            int m = mr + mi * 16 + r;
            bool ok = m < M;
            float di = 1.f, rdi = 1.f;
            if (SCALE) { di = dvi[mi]; if (RES) rdi = 1.f / di; }
            float u[4][4];
            #pragma unroll
            for (int j = 0; j < 4; j++)
                #pragma unroll
                for (int p = 0; p < 4; p++) {
                    float v = (SCALE ? di * acc[mi][j][p] : acc[mi][j][p]) + bq[j][p];
                    if (RELU) v = fmaxf(v, 0.f);
                    if (RES) v += bf2f(u4c(rv[t][mi][j], p)) * rdi;
                    if (SCALE == 1) v *= di;
                    u[j][p] = v;
                }

            if (OUTF32) {
                float c4[4][4], tf[4][4];
                #pragma unroll
                for (int j = 0; j < 4; j++)
                    #pragma unroll
                    for (int d = 0; d < 4; d++) c4[j][d] = u[j][d];
                #pragma unroll
                for (int j = 0; j < 4; j++)
                    #pragma unroll
                    for (int d = 0; d < 4; d++) tf[j][d] = __shfl_xor(c4[j ^ 1][d], 16);
                #pragma unroll
                for (int j = 0; j < 4; j++)
                    #pragma unroll
                    for (int d = 0; d < 4; d++)
                        c4[j][d] = (((j ^ q) & 1) == 0) ? c4[j][d] : tf[j][d];
                #pragma unroll
                for (int j = 0; j < 4; j++)
                    #pragma unroll
                    for (int d = 0; d < 4; d++) tf[j][d] = __shfl_xor(c4[j ^ 2][d], 32);
                #pragma unroll
                for (int j = 0; j < 4; j++)
                    #pragma unroll
                    for (int d = 0; d < 4; d++)
                        c4[j][d] = (((j ^ q) & 2) == 0) ? c4[j][d] : tf[j][d];
                if (ok) {
                    float* cp = (float*)Cout + (size_t)m * N + n0 + q * 16;
                    #pragma unroll
                    for (int j = 0; j < 4; j++) *(f32x4*)&cp[j * 4] = *(f32x4*)&c4[j][0];
                }
            } else {
                unsigned db[4][2], tb[4][2];
                #pragma unroll
                for (int j = 0; j < 4; j++) {
                    db[j][0] = pk2bf(u[j][0], u[j][1]);
                    db[j][1] = pk2bf(u[j][2], u[j][3]);
                }
                #pragma unroll
                for (int j = 0; j < 4; j++)
                    #pragma unroll
                    for (int d = 0; d < 2; d++) tb[j][d] = __shfl_xor((int)db[j ^ 1][d], 16);
                #pragma unroll
                for (int j = 0; j < 4; j++)
                    #pragma unroll
                    for (int d = 0; d < 2; d++)
                        db[j][d] = (((j ^ q) & 1) == 0) ? db[j][d] : tb[j][d];
                #pragma unroll
                for (int j = 0; j < 4; j++)
                    #pragma unroll
                    for (int d = 0; d < 2; d++) tb[j][d] = __shfl_xor((int)db[j ^ 2][d], 32);
                #pragma unroll
                for (int j = 0; j < 4; j++)
                    #pragma unroll
                    for (int d = 0; d < 2; d++)
                        db[j][d] = (((j ^ q) & 2) == 0) ? db[j][d] : tb[j][d];
                if (ok) {
                    unsigned short* cp = (unsigned short*)Cout + (size_t)m * N + n0 + q * 16;
                    *(uint4*)cp = make_uint4(db[0][0], db[0][1], db[1][0], db[1][1]);
                    *(uint4*)(cp + 8) = make_uint4(db[2][0], db[2][1], db[3][0], db[3][1]);
                }
                if (FP8O) {
                    unsigned f8[4], t8[4];
                    #pragma unroll
                    for (int j = 0; j < 4; j++) {
                        unsigned p8 = 0;
                        p8 = __builtin_amdgcn_cvt_pk_fp8_f32(u[j][0], u[j][1], p8, false);
                        p8 = __builtin_amdgcn_cvt_pk_fp8_f32(u[j][2], u[j][3], p8, true);
                        f8[j] = p8;
                    }
                    #pragma unroll
                    for (int j = 0; j < 4; j++) t8[j] = __shfl_xor((int)f8[j ^ 1], 16);
                    #pragma unroll
                    for (int j = 0; j < 4; j++)
                        f8[j] = (((j ^ q) & 1) == 0) ? f8[j] : t8[j];
                    #pragma unroll
                    for (int j = 0; j < 4; j++) t8[j] = __shfl_xor((int)f8[j ^ 2], 32);
                    #pragma unroll
                    for (int j = 0; j < 4; j++)
                        f8[j] = (((j ^ q) & 2) == 0) ? f8[j] : t8[j];
                    if (ok) {
                        unsigned char* fp = f8out + (size_t)m * N + n0 + q * 16;
                        *(uint4*)fp = make_uint4(f8[0], f8[1], f8[2], f8[3]);
                    }
                }
            }
        }
    }
}

// ---------------------------- pool / LN ------------------------------------

__launch_bounds__(256)
__global__ void pool_kernel(const unsigned short* __restrict__ h, const int* __restrict__ batch,
                            unsigned short* __restrict__ g0, int n, int G) {
    int g = blockIdx.x * 4 + (threadIdx.x >> 6);
    int lane = threadIdx.x & 63;
    if (g >= G) return;
    int lo = 0, hi = 0;
    if (lane == 0) {
        int a = 0, b = n;
        while (a < b) { int m = (a + b) >> 1; if (batch[m] < g) a = m + 1; else b = m; }
        lo = a;
        int a2 = a, b2 = n;
        while (a2 < b2) { int m = (a2 + b2) >> 1; if (batch[m] < g + 1) a2 = m + 1; else b2 = m; }
        hi = a2;
    }
    lo = __shfl(lo, 0); hi = __shfl(hi, 0);
    float a0 = 0.f, a1 = 0.f, a2 = 0.f, a3 = 0.f;
    for (int i = lo; i < hi; i++) {
        ushort4 v = *(const ushort4*)(h + (size_t)i * 256 + lane * 4);
        a0 += bf2f(v.x); a1 += bf2f(v.y); a2 += bf2f(v.z); a3 += bf2f(v.w);
    }
    float inv = 1.0f / fmaxf((float)(hi - lo), 1.0f);
    ushort4 o;
    o.x = f2bf(a0 * inv); o.y = f2bf(a1 * inv); o.z = f2bf(a2 * inv); o.w = f2bf(a3 * inv);
    *(ushort4*)(g0 + (size_t)g * 256 + lane * 4) = o;
}

__launch_bounds__(256)
__global__ void ln_kernel(const float* __restrict__ g2, const float* __restrict__ gamma,
                          const float* __restrict__ beta, float* __restrict__ out, int rows) {
    int row = blockIdx.x * 4 + (threadIdx.x >> 6);
    int lane = threadIdx.x & 63;
    if (row >= rows) return;
    const float* r = g2 + (size_t)row * 768;
    float v[12];
    float s = 0.f, s2 = 0.f;
    #pragma unroll
    for (int j = 0; j < 12; j++) {
        v[j] = r[lane + 64 * j];
        s += v[j];
        s2 += v[j] * v[j];
    }
    #pragma unroll
    for (int off = 32; off > 0; off >>= 1) {
        s += __shfl_down(s, off);
        s2 += __shfl_down(s2, off);
    }
    s = __shfl(s, 0);
    s2 = __shfl(s2, 0);
    float mu = s * (1.0f / 768.0f);
    float var = s2 * (1.0f / 768.0f) - mu * mu;
    float inv = rsqrtf(var + 1e-5f);
    #pragma unroll
    for (int j = 0; j < 12; j++) {
        int c = lane + 64 * j;
        out[(size_t)row * 768 + c] = (v[j] - mu) * inv * gamma[c] + beta[c];
    }
}

// ---------------------------------------------------------------------------

extern "C" void kernel_launch(void* const* d_in, const int* in_sizes, int n_in,
                              void* d_out, int out_size, void* d_ws, size_t ws_size,
                              hipStream_t stream) {
    const float* x    = (const float*)d_in[0];
    const int* eidx   = (const int*)d_in[1];
    const int* batch  = (const int*)d_in[2];
    const float* W1   = (const float*)d_in[3];
    const float* b1   = (const float*)d_in[4];
    const float* W2   = (const float*)d_in[5];
    const float* b2   = (const float*)d_in[6];
    const float* W3   = (const float*)d_in[7];
    const float* b3   = (const float*)d_in[8];
    const float* P1   = (const float*)d_in[9];
    const float* pb1  = (const float*)d_in[10];
    const float* P2   = (const float*)d_in[11];
    const float* pb2  = (const float*)d_in[12];
    const float* ln_g = (const float*)d_in[13];
    const float* ln_b = (const float*)d_in[14];
    float* out = (float*)d_out;

    const int N = in_sizes[2];            // 50000
    const int E = in_sizes[1] / 2;        // 800000
    const int F_IN = in_sizes[0] / N;     // 128
    const int H = in_sizes[4];            // 256
    const int D = in_sizes[12];           // 768
    const int G = out_size / D;           // 1024
    const int NPAD = (N + 127) & ~127;
    const int NB = (N + 511) / 512;       // scan blocks (<=128)

    const int* src = eidx;
    const int* dst = eidx + E;

    char* ws = (char*)d_ws;
    size_t off = 0;
    auto alloc = [&](size_t bytes) -> char* {
        char* p = ws + off;
        off = (off + bytes + 255) & ~(size_t)255;
        return p;
    };
    int*   cnt      = (int*)alloc((size_t)NPAD * 4);
    float* dinv     = (float*)alloc((size_t)NPAD * 4);
    int*   row_ptr  = (int*)alloc((size_t)(N + 1) * 4);
    int*   bsum     = (int*)alloc(128 * 4);
    int*   rank     = (int*)alloc((size_t)E * 4);
    int*   csr      = (int*)alloc((size_t)E * 4);
    unsigned char* xf8  = (unsigned char*)alloc((size_t)(N + 1) * F_IN);      // x̂ fp8, +dummy
    unsigned char* h1f8 = (unsigned char*)alloc((size_t)(N + 1) * H);         // ĥ1 fp8, +dummy
    unsigned char* h2f8 = (unsigned char*)alloc((size_t)(N + 1) * H);         // ĥ2 fp8, +dummy
    unsigned short* Wt1 = (unsigned short*)alloc((size_t)F_IN * H * 2);
    unsigned short* Wt2 = (unsigned short*)alloc((size_t)H * H * 2);
    unsigned short* Wt3 = (unsigned short*)alloc((size_t)H * H * 2);
    unsigned short* Pt1 = (unsigned short*)alloc((size_t)H * H * 2);
    unsigned short* Pt2 = (unsigned short*)alloc((size_t)H * D * 2);
    unsigned short* t1  = (unsigned short*)alloc((size_t)N * F_IN * 2);       // Σ x̂ (bf16)
    unsigned short* tA  = (unsigned short*)alloc((size_t)N * H * 2);          // Σ ĥ (bf16)
    unsigned short* hh1 = (unsigned short*)alloc((size_t)N * H * 2);          // ĥ1 bf16 (residual)
    unsigned short* hh2 = (unsigned short*)alloc((size_t)N * H * 2);          // ĥ2 bf16 (residual)
    unsigned short* h3  = (unsigned short*)alloc((size_t)N * H * 2);
    unsigned short* g0b = (unsigned short*)alloc((size_t)G * H * 2);
    unsigned short* g1b = (unsigned short*)alloc((size_t)G * H * 2);
    float* g2 = (float*)alloc((size_t)G * D * 4);
    (void)ws_size; (void)n_in;

    // --- CSR build -----------------------------------------------------------
    hipMemsetAsync(cnt, 0, (size_t)NPAD * 4, stream);
    count_kernel<<<(E + 255) / 256, 256, 0, stream>>>(dst, E, cnt, rank);
    scanA<<<NB, 512, 0, stream>>>(cnt, N, bsum, dinv);
    scanC<<<NB, 512, 0, stream>>>(cnt, N, bsum, E, row_ptr);

    // --- fused scatter + conversions (one launch) ---------------------------
    {
        int n4 = N * F_IN / 4;
        int tot = F_IN * H + 3 * H * H + H * D;
        int total = E + n4 + tot + 640;
        convert_all<<<(total + 255) / 256, 256, 0, stream>>>(
            src, dst, row_ptr, rank, csr, E,
            x, dinv, xf8, n4, W1, W2, W3, P1, P2, Wt1, Wt2, Wt3, Pt1, Pt2, F_IN, H, D,
            xf8 + (size_t)N * F_IN, h1f8 + (size_t)N * H, h2f8 + (size_t)N * H);
    }

    // --- GCN layers (aggregate-first, ĥ-space, fp8 gathers) -----------------
    int agg_grid = (N + 3) / 4;
    int mtiles = (N + 63) / 64;           // 128-thr wgemm blocks: 64 rows each

    // layer 1: t1 = x̂[i] + Σ x̂[src]; ĥ1 = di*relu(di*(t1 W1) + b1)  (+fp8)
    aggregate128<<<agg_grid, 256, 0, stream>>>(xf8, row_ptr, csr, t1, N, N);
    wgemm<128, 2, 1, 0, 0, 1, 1><<<dim3(2, mtiles), 128, 0, stream>>>(t1, Wt1, b1, nullptr, dinv, hh1, h1f8, N, H);

    // layer 2: t2 = ĥ1[i] + Σ ĥ1[src]; ĥ2 = di*(relu(di*(t2 W2)+b2) + ĥ1/di)
    aggregate256<<<agg_grid, 256, 0, stream>>>(h1f8, row_ptr, csr, tA, N, N);
    wgemm<256, 2, 1, 1, 0, 1, 1><<<dim3(2, mtiles), 128, 0, stream>>>(tA, Wt2, b2, hh1, dinv, hh2, h2f8, N, H);

    // layer 3: t3 = ĥ2[i] + Σ ĥ2[src]; h3 = relu(di*(t3 W3)+b3) + ĥ2/di
    aggregate256<<<agg_grid, 256, 0, stream>>>(h2f8, row_ptr, csr, tA, N, N);
    wgemm<256, 2, 1, 1, 0, 2, 0><<<dim3(2, mtiles), 128, 0, stream>>>(tA, Wt3, b3, hh2, dinv, h3, nullptr, N, H);

    // --- pool + MLP + LN -----------------------------------------------------
    pool_kernel<<<(G + 3) / 4, 256, 0, stream>>>(h3, batch, g0b, N, G);
    wgemm<256, 1, 1, 0, 0, 0, 0><<<dim3(4, G / 64), 128, 0, stream>>>(g0b, Pt1, pb1, nullptr, nullptr, g1b, nullptr, G, H);
    wgemm<256, 1, 0, 0, 1, 0, 0><<<dim3(12, G / 64), 128, 0, stream>>>(g1b, Pt2, pb2, nullptr, nullptr, g2, nullptr, G, D);
    ln_kernel<<<G / 4, 256, 0, stream>>>(g2, ln_g, ln_b, out, G);
}

// Round 6
// 358.501 us; speedup vs baseline: 1.0252x; 1.0252x over previous
//
#include <hip/hip_runtime.h>

// ---------------------------------------------------------------------------
// GraphEncoder round 20: wgemm reverted to R18 exact (measured best 363.9).
// Aggregate VGPR/occupancy fix: R15 showed aggregates are latency-bound, and
// the j-loop's live state (~58-70 VGPR incl. 8x 64-bit addresses from size_t
// per-lane address math) straddles the 64-VGPR occupancy cliff (8->4
// waves/SIMD). Changes: (1) gathers use uniform-base + 32-bit offset (SADDR
// form, 1 VGPR/addr) -> ~8 fewer live VGPRs; (2) accumulation in f32x2 with
// v_pk_add_f32 (same regs, 2/3 the VALU).
// ---------------------------------------------------------------------------

typedef __attribute__((ext_vector_type(8))) short short8;
typedef __attribute__((ext_vector_type(4))) float f32x4;
typedef __attribute__((ext_vector_type(2))) float f32x2;

__device__ __forceinline__ float bf2f(unsigned short s) {
    union { unsigned u; float f; } v;
    v.u = ((unsigned)s) << 16;
    return v.f;
}
__device__ __forceinline__ unsigned short f2bf(float f) {
    union { float f; unsigned u; } v;
    v.f = f;
    unsigned r = (v.u + 0x7FFFu + ((v.u >> 16) & 1u)) >> 16;
    return (unsigned short)r;
}
__device__ __forceinline__ unsigned pk2bf(float lo, float hi) {
    return (unsigned)f2bf(lo) | ((unsigned)f2bf(hi) << 16);
}
__device__ __forceinline__ unsigned short u4c(ushort4 v, int p) {
    return p == 0 ? v.x : p == 1 ? v.y : p == 2 ? v.z : v.w;
}

// accumulate 8 fp8 values (two packed dwords) into acc2[0..4) (f32x2 lanes)
__device__ __forceinline__ void acc8_fp8(unsigned int lo, unsigned int hi, f32x2* acc2) {
    acc2[0] += __builtin_amdgcn_cvt_pk_f32_fp8(lo, false);
    acc2[1] += __builtin_amdgcn_cvt_pk_f32_fp8(lo, true);
    acc2[2] += __builtin_amdgcn_cvt_pk_f32_fp8(hi, false);
    acc2[3] += __builtin_amdgcn_cvt_pk_f32_fp8(hi, true);
}

// ---------------------------- CSR build ------------------------------------

__global__ void count_kernel(const int* __restrict__ dst, int E, int* __restrict__ cnt,
                             int* __restrict__ rank) {
    int e = blockIdx.x * blockDim.x + threadIdx.x;
    if (e < E) rank[e] = atomicAdd(&cnt[dst[e]], 1);
}

__global__ void scanA(const int* __restrict__ cnt, int n, int* __restrict__ bsum,
                      float* __restrict__ dinv) {
    int tid = threadIdx.x, lane = tid & 63, w = tid >> 6;
    int i = blockIdx.x * 512 + tid;
    int v = (i < n) ? cnt[i] : 0;
    if (i < n) dinv[i] = rsqrtf((float)v + 1.0f);
    int s = v;
    #pragma unroll
    for (int off = 1; off < 64; off <<= 1) s += __shfl_xor(s, off);
    __shared__ int ws[8];
    if (lane == 0) ws[w] = s;
    __syncthreads();
    if (tid == 0) {
        int t = 0;
        #pragma unroll
        for (int j = 0; j < 8; j++) t += ws[j];
        bsum[blockIdx.x] = t;
    }
}

__global__ void scanC(const int* __restrict__ cnt, int n, const int* __restrict__ bsum,
                      int E, int* __restrict__ row_ptr) {
    int tid = threadIdx.x, lane = tid & 63, w = tid >> 6;
    int i = blockIdx.x * 512 + tid;
    __shared__ int s_boff;
    if (tid < 64) {
        int acc = 0;
        for (int b = tid; b < blockIdx.x; b += 64) acc += bsum[b];
        #pragma unroll
        for (int off = 1; off < 64; off <<= 1) acc += __shfl_xor(acc, off);
        if (tid == 0) s_boff = acc;
    }
    int v = (i < n) ? cnt[i] : 0;
    int incl = v;
    #pragma unroll
    for (int off = 1; off < 64; off <<= 1) {
        int t = __shfl_up(incl, off);
        if (lane >= off) incl += t;
    }
    __shared__ int ws[8];
    if (lane == 63) ws[w] = incl;
    __syncthreads();
    int woff = 0;
    for (int j = 0; j < w; j++) woff += ws[j];
    if (i < n) row_ptr[i] = s_boff + woff + incl - v;
    if (blockIdx.x == 0 && tid == 0) row_ptr[n] = E;
}

// ---------------------------- fused scatter + conversions ------------------

__global__ void convert_all(const int* __restrict__ src, const int* __restrict__ dst,
                            const int* __restrict__ row_ptr, const int* __restrict__ rank,
                            int* __restrict__ csr, int E,
                            const float* __restrict__ x, const float* __restrict__ dinv,
                            unsigned char* __restrict__ xf8, int n4,
                            const float* __restrict__ W1, const float* __restrict__ W2,
                            const float* __restrict__ W3, const float* __restrict__ P1,
                            const float* __restrict__ P2,
                            unsigned short* __restrict__ Wt1, unsigned short* __restrict__ Wt2,
                            unsigned short* __restrict__ Wt3, unsigned short* __restrict__ Pt1,
                            unsigned short* __restrict__ Pt2,
                            int F_IN, int H, int D,
                            unsigned char* __restrict__ zx,
                            unsigned char* __restrict__ z1,
                            unsigned char* __restrict__ z2) {
    int gidx = blockIdx.x * blockDim.x + threadIdx.x;
    if (gidx < E) {
        csr[row_ptr[dst[gidx]] + rank[gidx]] = src[gidx];
        return;
    }
    int idx = gidx - E;
    if (idx < n4) {
        float di = dinv[idx >> 5];
        float4 v = ((const float4*)x)[idx];
        unsigned int p = 0;
        p = __builtin_amdgcn_cvt_pk_fp8_f32(di * v.x, di * v.y, p, false);
        p = __builtin_amdgcn_cvt_pk_fp8_f32(di * v.z, di * v.w, p, true);
        ((unsigned int*)xf8)[idx] = p;
        return;
    }
    int t = idx - n4;
    int n1 = F_IN * H, n2 = H * H, n5 = H * D;
    const float* W; unsigned short* O; int N;
    if (t < n1)              { W = W1; O = Wt1; N = H; }
    else if ((t -= n1) < n2) { W = W2; O = Wt2; N = H; }
    else if ((t -= n2) < n2) { W = W3; O = Wt3; N = H; }
    else if ((t -= n2) < n2) { W = P1; O = Pt1; N = H; }
    else if ((t -= n2) < n5) { W = P2; O = Pt2; N = D; }
    else {
        t -= n5;
        if (t < 128) zx[t] = 0;
        else if (t < 384) z1[t - 128] = 0;
        else if (t < 640) z2[t - 384] = 0;
        return;
    }
    int k = t / N, n = t - k * N;
    int K = (W == W1) ? F_IN : H;
    O[(size_t)n * K + k] = f2bf(W[t]);
}

// ---------------------------- aggregation (fp8 gathers) --------------------
// R14 shape; gathers via uniform base + u32 offset (SADDR form, 1 VGPR/addr);
// f32x2 packed accumulation.

__launch_bounds__(256)
__global__ void aggregate256(const unsigned char* __restrict__ hf8,
                             const int* __restrict__ row_ptr,
                             const int* __restrict__ csr,
                             unsigned short* __restrict__ out, int n, int zrow) {
    int node = blockIdx.x * 4 + (threadIdx.x >> 6);
    int lane = threadIdx.x & 63;
    if (node >= n) return;
    int half = lane >> 5;          // which edge of the pair
    int cl = lane & 31;            // 8-col chunk
    f32x2 acc2[4];
    #pragma unroll
    for (int c = 0; c < 4; c++) acc2[c] = (f32x2){0.f, 0.f};
    if (half == 0) {
        uint2 sv = *(const uint2*)(hf8 + ((unsigned)node * 256u + (unsigned)cl * 8u));
        acc8_fp8(sv.x, sv.y, acc2);
    }
    int beg = row_ptr[node], end = row_ptr[node + 1];
    for (int base = beg; base < end; base += 64) {
        int k = base + lane;
        int mi = (k < end) ? csr[k] : zrow;
        int cnt = min(64, end - base);
        for (int j = 0; j < cnt; j += 16) {
            unsigned off[8]; uint2 vv[8];
            #pragma unroll
            for (int u = 0; u < 8; u++)
                off[u] = (unsigned)__shfl(mi, j + 2 * u + half) * 256u + (unsigned)cl * 8u;
            #pragma unroll
            for (int u = 0; u < 8; u++) vv[u] = *(const uint2*)(hf8 + off[u]);
            #pragma unroll
            for (int u = 0; u < 8; u++) acc8_fp8(vv[u].x, vv[u].y, acc2);
        }
    }
    #pragma unroll
    for (int c = 0; c < 4; c++) {
        acc2[c][0] += __shfl_xor(acc2[c][0], 32);
        acc2[c][1] += __shfl_xor(acc2[c][1], 32);
    }
    if (half == 0) {
        short8 o;
        #pragma unroll
        for (int c = 0; c < 8; c++) o[c] = (short)f2bf(acc2[c >> 1][c & 1]);
        *(short8*)(out + (size_t)node * 256 + cl * 8) = o;
    }
}

__launch_bounds__(256)
__global__ void aggregate128(const unsigned char* __restrict__ hf8,
                             const int* __restrict__ row_ptr,
                             const int* __restrict__ csr,
                             unsigned short* __restrict__ out, int n, int zrow) {
    int node = blockIdx.x * 4 + (threadIdx.x >> 6);
    int lane = threadIdx.x & 63;
    if (node >= n) return;
    int qtr = lane >> 4;           // which edge of the quad
    int cl = lane & 15;            // 8-col chunk
    f32x2 acc2[4];
    #pragma unroll
    for (int c = 0; c < 4; c++) acc2[c] = (f32x2){0.f, 0.f};
    if (qtr == 0) {
        uint2 sv = *(const uint2*)(hf8 + ((unsigned)node * 128u + (unsigned)cl * 8u));
        acc8_fp8(sv.x, sv.y, acc2);
    }
    int beg = row_ptr[node], end = row_ptr[node + 1];
    for (int base = beg; base < end; base += 64) {
        int k = base + lane;
        int mi = (k < end) ? csr[k] : zrow;
        int cnt = min(64, end - base);
        for (int j = 0; j < cnt; j += 32) {
            unsigned off[8]; uint2 vv[8];
            #pragma unroll
            for (int u = 0; u < 8; u++)
                off[u] = (unsigned)__shfl(mi, j + 4 * u + qtr) * 128u + (unsigned)cl * 8u;
            #pragma unroll
            for (int u = 0; u < 8; u++) vv[u] = *(const uint2*)(hf8 + off[u]);
            #pragma unroll
            for (int u = 0; u < 8; u++) acc8_fp8(vv[u].x, vv[u].y, acc2);
        }
    }
    #pragma unroll
    for (int c = 0; c < 4; c++) {
        acc2[c][0] += __shfl_xor(acc2[c][0], 16);
        acc2[c][1] += __shfl_xor(acc2[c][1], 16);
        acc2[c][0] += __shfl_xor(acc2[c][0], 32);
        acc2[c][1] += __shfl_xor(acc2[c][1], 32);
    }
    if (qtr == 0) {
        short8 o;
        #pragma unroll
        for (int c = 0; c < 8; c++) o[c] = (short)f2bf(acc2[c >> 1][c & 1]);
        *(short8*)(out + (size_t)node * 128 + cl * 8) = o;
    }
}

// ---------------------------- wgemm (R18, measured best) -------------------
// C = epi(A[M,K] @ Bt[N,K]^T). 256-thr blocks = 4 waves x 32 rows (128 rows).
// A frags in registers; per 64-col tile B staged to LDS with XOR-swizzled
// 16B chunk slots (slot = ch ^ (row&7); row stride = K shorts) ->
// conflict-free ds_read_b128 b-frags. Swapped-operand MFMA -> C^T frags;
// register-only butterfly transpose epilogue. ntiles=2: one A-frag load
// serves two 64-col tiles.
// SCALE: 0 plain; 1: v=relu(di*acc+b)[+res/di], store di*v; 2: ...store v.
// FP8O: also store v as fp8 shadow (gather copy for the next aggregate).

template<int K, int RELU, int RES, int OUTF32, int SCALE, int FP8O>
__launch_bounds__(256)
__global__ void wgemm(const unsigned short* __restrict__ A,
                      const unsigned short* __restrict__ Bt,
                      const float* __restrict__ bias,
                      const unsigned short* __restrict__ residual,
                      const float* __restrict__ dinv,
                      void* __restrict__ Cout,
                      unsigned char* __restrict__ f8out,
                      int M, int N, int ntiles) {
    constexpr int KK = K / 32;
    constexpr int CPR = K / 8;
    __shared__ __align__(16) unsigned short Bs[64 * K];

    int tid = threadIdx.x;
    int wave = tid >> 6, lane = tid & 63;
    int r = lane & 15, q = lane >> 4;
    int mr = blockIdx.y * 128 + wave * 32;
    int nbase = blockIdx.x * ntiles * 64;

    short8 a[2][KK];
    #pragma unroll
    for (int mi = 0; mi < 2; mi++) {
        int arow = mr + mi * 16 + r;
        bool aok = arow < M;
        const unsigned short* ap = A + (size_t)(aok ? arow : 0) * K;
        #pragma unroll
        for (int kk = 0; kk < KK; kk++) {
            short8 v = *(const short8*)(ap + kk * 32 + q * 8);
            if (!aok) v = (short8){0, 0, 0, 0, 0, 0, 0, 0};
            a[mi][kk] = v;
        }
    }

    for (int t = 0; t < ntiles; t++) {
        int n0 = nbase + t * 64;
        if (t > 0) __syncthreads();
        #pragma unroll
        for (int pass = 0; pass < 64 * CPR / 256; pass++) {
            int f = pass * 256 + tid;
            int row = f / CPR, ch = f % CPR;
            *(short8*)&Bs[row * K + (ch ^ (row & 7)) * 8] =
                *(const short8*)(Bt + (size_t)(n0 + row) * K + ch * 8);
        }
        __syncthreads();

        f32x4 acc[2][4];
        #pragma unroll
        for (int mi = 0; mi < 2; mi++)
            #pragma unroll
            for (int j = 0; j < 4; j++) acc[mi][j] = (f32x4){0.f, 0.f, 0.f, 0.f};

        #pragma unroll
        for (int kk = 0; kk < KK; kk++) {
            short8 b[4];
            #pragma unroll
            for (int j = 0; j < 4; j++)
                b[j] = *(short8*)&Bs[(j * 16 + r) * K + ((kk * 4 + q) ^ (r & 7)) * 8];
            #pragma unroll
            for (int mi = 0; mi < 2; mi++)
                #pragma unroll
                for (int j = 0; j < 4; j++)
                    acc[mi][j] = __builtin_amdgcn_mfma_f32_16x16x32_bf16(b[j], a[mi][kk], acc[mi][j], 0, 0, 0);
        }

        // --- epilogue (register-only) ---
        // lane(q,r), reg p of acc[mi][j]: C[m = mr+mi*16+r][n = n0+j*16+q*4+p]
        f32x4 bq[4];
        #pragma unroll
        for (int j = 0; j < 4; j++)
            bq[j] = *(const f32x4*)&bias[n0 + j * 16 + q * 4];

        #pragma unroll
        for (int mi = 0; mi < 2; mi++) {
            int m = mr + mi * 16 + r;
            bool ok = m < M;
            float di = 1.f, rdi = 1.f;
            if (SCALE) { di = dinv[ok ? m : 0]; if (RES) rdi = 1.f / di; }
            ushort4 rv[4];
            if (RES) {
                const unsigned short* rp = residual + (size_t)(ok ? m : 0) * N + n0 + q * 4;
                #pragma unroll
                for (int j = 0; j < 4; j++) rv[j] = *(const ushort4*)(rp + j * 16);
            }
            float u[4][4];
            #pragma unroll
            for (int j = 0; j < 4; j++)
                #pragma unroll
                for (int p = 0; p < 4; p++) {
                    float v = (SCALE ? di * acc[mi][j][p] : acc[mi][j][p]) + bq[j][p];
                    if (RELU) v = fmaxf(v, 0.f);
                    if (RES) v += bf2f(u4c(rv[j], p)) * rdi;
                    if (SCALE == 1) v *= di;
                    u[j][p] = v;
                }

            if (OUTF32) {
                float c4[4][4], tf[4][4];
                #pragma unroll
                for (int j = 0; j < 4; j++)
                    #pragma unroll
                    for (int d = 0; d < 4; d++) c4[j][d] = u[j][d];
                #pragma unroll
                for (int j = 0; j < 4; j++)
                    #pragma unroll
                    for (int d = 0; d < 4; d++) tf[j][d] = __shfl_xor(c4[j ^ 1][d], 16);
                #pragma unroll
                for (int j = 0; j < 4; j++)
                    #pragma unroll
                    for (int d = 0; d < 4; d++)
                        c4[j][d] = (((j ^ q) & 1) == 0) ? c4[j][d] : tf[j][d];
                #pragma unroll
                for (int j = 0; j < 4; j++)
                    #pragma unroll
                    for (int d = 0; d < 4; d++) tf[j][d] = __shfl_xor(c4[j ^ 2][d], 32);
                #pragma unroll
                for (int j = 0; j < 4; j++)
                    #pragma unroll
                    for (int d = 0; d < 4; d++)
                        c4[j][d] = (((j ^ q) & 2) == 0) ? c4[j][d] : tf[j][d];
                if (ok) {
                    float* cp = (float*)Cout + (size_t)m * N + n0 + q * 16;
                    #pragma unroll
                    for (int j = 0; j < 4; j++) *(f32x4*)&cp[j * 4] = *(f32x4*)&c4[j][0];
                }
            } else {
                unsigned db[4][2], tb[4][2];
                #pragma unroll
                for (int j = 0; j < 4; j++) {
                    db[j][0] = pk2bf(u[j][0], u[j][1]);
                    db[j][1] = pk2bf(u[j][2], u[j][3]);
                }
                #pragma unroll
                for (int j = 0; j < 4; j++)
                    #pragma unroll
                    for (int d = 0; d < 2; d++) tb[j][d] = __shfl_xor((int)db[j ^ 1][d], 16);
                #pragma unroll
                for (int j = 0; j < 4; j++)
                    #pragma unroll
                    for (int d = 0; d < 2; d++)
                        db[j][d] = (((j ^ q) & 1) == 0) ? db[j][d] : tb[j][d];
                #pragma unroll
                for (int j = 0; j < 4; j++)
                    #pragma unroll
                    for (int d = 0; d < 2; d++) tb[j][d] = __shfl_xor((int)db[j ^ 2][d], 32);
                #pragma unroll
                for (int j = 0; j < 4; j++)
                    #pragma unroll
                    for (int d = 0; d < 2; d++)
                        db[j][d] = (((j ^ q) & 2) == 0) ? db[j][d] : tb[j][d];
                if (ok) {
                    unsigned short* cp = (unsigned short*)Cout + (size_t)m * N + n0 + q * 16;
                    *(uint4*)cp = make_uint4(db[0][0], db[0][1], db[1][0], db[1][1]);
                    *(uint4*)(cp + 8) = make_uint4(db[2][0], db[2][1], db[3][0], db[3][1]);
                }
                if (FP8O) {
                    unsigned f8[4], t8[4];
                    #pragma unroll
                    for (int j = 0; j < 4; j++) {
                        unsigned p8 = 0;
                        p8 = __builtin_amdgcn_cvt_pk_fp8_f32(u[j][0], u[j][1], p8, false);
                        p8 = __builtin_amdgcn_cvt_pk_fp8_f32(u[j][2], u[j][3], p8, true);
                        f8[j] = p8;
                    }
                    #pragma unroll
                    for (int j = 0; j < 4; j++) t8[j] = __shfl_xor((int)f8[j ^ 1], 16);
                    #pragma unroll
                    for (int j = 0; j < 4; j++)
                        f8[j] = (((j ^ q) & 1) == 0) ? f8[j] : t8[j];
                    #pragma unroll
                    for (int j = 0; j < 4; j++) t8[j] = __shfl_xor((int)f8[j ^ 2], 32);
                    #pragma unroll
                    for (int j = 0; j < 4; j++)
                        f8[j] = (((j ^ q) & 2) == 0) ? f8[j] : t8[j];
                    if (ok) {
                        unsigned char* fp = f8out + (size_t)m * N + n0 + q * 16;
                        *(uint4*)fp = make_uint4(f8[0], f8[1], f8[2], f8[3]);
                    }
                }
            }
        }
    }
}

// ---------------------------- pool / LN ------------------------------------

__launch_bounds__(256)
__global__ void pool_kernel(const unsigned short* __restrict__ h, const int* __restrict__ batch,
                            unsigned short* __restrict__ g0, int n, int G) {
    int g = blockIdx.x * 4 + (threadIdx.x >> 6);
    int lane = threadIdx.x & 63;
    if (g >= G) return;
    int lo = 0, hi = 0;
    if (lane == 0) {
        int a = 0, b = n;
        while (a < b) { int m = (a + b) >> 1; if (batch[m] < g) a = m + 1; else b = m; }
        lo = a;
        int a2 = a, b2 = n;
        while (a2 < b2) { int m = (a2 + b2) >> 1; if (batch[m] < g + 1) a2 = m + 1; else b2 = m; }
        hi = a2;
    }
    lo = __shfl(lo, 0); hi = __shfl(hi, 0);
    float a0 = 0.f, a1 = 0.f, a2 = 0.f, a3 = 0.f;
    for (int i = lo; i < hi; i++) {
        ushort4 v = *(const ushort4*)(h + (size_t)i * 256 + lane * 4);
        a0 += bf2f(v.x); a1 += bf2f(v.y); a2 += bf2f(v.z); a3 += bf2f(v.w);
    }
    float inv = 1.0f / fmaxf((float)(hi - lo), 1.0f);
    ushort4 o;
    o.x = f2bf(a0 * inv); o.y = f2bf(a1 * inv); o.z = f2bf(a2 * inv); o.w = f2bf(a3 * inv);
    *(ushort4*)(g0 + (size_t)g * 256 + lane * 4) = o;
}

__launch_bounds__(256)
__global__ void ln_kernel(const float* __restrict__ g2, const float* __restrict__ gamma,
                          const float* __restrict__ beta, float* __restrict__ out, int rows) {
    int row = blockIdx.x * 4 + (threadIdx.x >> 6);
    int lane = threadIdx.x & 63;
    if (row >= rows) return;
    const float* r = g2 + (size_t)row * 768;
    float v[12];
    float s = 0.f, s2 = 0.f;
    #pragma unroll
    for (int j = 0; j < 12; j++) {
        v[j] = r[lane + 64 * j];
        s += v[j];
        s2 += v[j] * v[j];
    }
    #pragma unroll
    for (int off = 32; off > 0; off >>= 1) {
        s += __shfl_down(s, off);
        s2 += __shfl_down(s2, off);
    }
    s = __shfl(s, 0);
    s2 = __shfl(s2, 0);
    float mu = s * (1.0f / 768.0f);
    float var = s2 * (1.0f / 768.0f) - mu * mu;
    float inv = rsqrtf(var + 1e-5f);
    #pragma unroll
    for (int j = 0; j < 12; j++) {
        int c = lane + 64 * j;
        out[(size_t)row * 768 + c] = (v[j] - mu) * inv * gamma[c] + beta[c];
    }
}

// ---------------------------------------------------------------------------

extern "C" void kernel_launch(void* const* d_in, const int* in_sizes, int n_in,
                              void* d_out, int out_size, void* d_ws, size_t ws_size,
                              hipStream_t stream) {
    const float* x    = (const float*)d_in[0];
    const int* eidx   = (const int*)d_in[1];
    const int* batch  = (const int*)d_in[2];
    const float* W1   = (const float*)d_in[3];
    const float* b1   = (const float*)d_in[4];
    const float* W2   = (const float*)d_in[5];
    const float* b2   = (const float*)d_in[6];
    const float* W3   = (const float*)d_in[7];
    const float* b3   = (const float*)d_in[8];
    const float* P1   = (const float*)d_in[9];
    const float* pb1  = (const float*)d_in[10];
    const float* P2   = (const float*)d_in[11];
    const float* pb2  = (const float*)d_in[12];
    const float* ln_g = (const float*)d_in[13];
    const float* ln_b = (const float*)d_in[14];
    float* out = (float*)d_out;

    const int N = in_sizes[2];            // 50000
    const int E = in_sizes[1] / 2;        // 800000
    const int F_IN = in_sizes[0] / N;     // 128
    const int H = in_sizes[4];            // 256
    const int D = in_sizes[12];           // 768
    const int G = out_size / D;           // 1024
    const int NPAD = (N + 127) & ~127;
    const int NB = (N + 511) / 512;       // scan blocks (<=128)

    const int* src = eidx;
    const int* dst = eidx + E;

    char* ws = (char*)d_ws;
    size_t off = 0;
    auto alloc = [&](size_t bytes) -> char* {
        char* p = ws + off;
        off = (off + bytes + 255) & ~(size_t)255;
        return p;
    };
    int*   cnt      = (int*)alloc((size_t)NPAD * 4);
    float* dinv     = (float*)alloc((size_t)NPAD * 4);
    int*   row_ptr  = (int*)alloc((size_t)(N + 1) * 4);
    int*   bsum     = (int*)alloc(128 * 4);
    int*   rank     = (int*)alloc((size_t)E * 4);
    int*   csr      = (int*)alloc((size_t)E * 4);
    unsigned char* xf8  = (unsigned char*)alloc((size_t)(N + 1) * F_IN);      // x̂ fp8, +dummy
    unsigned char* h1f8 = (unsigned char*)alloc((size_t)(N + 1) * H);         // ĥ1 fp8, +dummy
    unsigned char* h2f8 = (unsigned char*)alloc((size_t)(N + 1) * H);         // ĥ2 fp8, +dummy
    unsigned short* Wt1 = (unsigned short*)alloc((size_t)F_IN * H * 2);
    unsigned short* Wt2 = (unsigned short*)alloc((size_t)H * H * 2);
    unsigned short* Wt3 = (unsigned short*)alloc((size_t)H * H * 2);
    unsigned short* Pt1 = (unsigned short*)alloc((size_t)H * H * 2);
    unsigned short* Pt2 = (unsigned short*)alloc((size_t)H * D * 2);
    unsigned short* t1  = (unsigned short*)alloc((size_t)N * F_IN * 2);       // Σ x̂ (bf16)
    unsigned short* tA  = (unsigned short*)alloc((size_t)N * H * 2);          // Σ ĥ (bf16)
    unsigned short* hh1 = (unsigned short*)alloc((size_t)N * H * 2);          // ĥ1 bf16 (residual)
    unsigned short* hh2 = (unsigned short*)alloc((size_t)N * H * 2);          // ĥ2 bf16 (residual)
    unsigned short* h3  = (unsigned short*)alloc((size_t)N * H * 2);
    unsigned short* g0b = (unsigned short*)alloc((size_t)G * H * 2);
    unsigned short* g1b = (unsigned short*)alloc((size_t)G * H * 2);
    float* g2 = (float*)alloc((size_t)G * D * 4);
    (void)ws_size; (void)n_in;

    // --- CSR build -----------------------------------------------------------
    hipMemsetAsync(cnt, 0, (size_t)NPAD * 4, stream);
    count_kernel<<<(E + 255) / 256, 256, 0, stream>>>(dst, E, cnt, rank);
    scanA<<<NB, 512, 0, stream>>>(cnt, N, bsum, dinv);
    scanC<<<NB, 512, 0, stream>>>(cnt, N, bsum, E, row_ptr);

    // --- fused scatter + conversions (one launch) ---------------------------
    {
        int n4 = N * F_IN / 4;
        int tot = F_IN * H + 3 * H * H + H * D;
        int total = E + n4 + tot + 640;
        convert_all<<<(total + 255) / 256, 256, 0, stream>>>(
            src, dst, row_ptr, rank, csr, E,
            x, dinv, xf8, n4, W1, W2, W3, P1, P2, Wt1, Wt2, Wt3, Pt1, Pt2, F_IN, H, D,
            xf8 + (size_t)N * F_IN, h1f8 + (size_t)N * H, h2f8 + (size_t)N * H);
    }

    // --- GCN layers (aggregate-first, ĥ-space, fp8 gathers) -----------------
    int agg_grid = (N + 3) / 4;
    int mtiles = (N + 127) / 128;

    // layer 1: t1 = x̂[i] + Σ x̂[src]; ĥ1 = di*relu(di*(t1 W1) + b1)  (+fp8)
    aggregate128<<<agg_grid, 256, 0, stream>>>(xf8, row_ptr, csr, t1, N, N);
    wgemm<128, 1, 0, 0, 1, 1><<<dim3(2, mtiles), 256, 0, stream>>>(t1, Wt1, b1, nullptr, dinv, hh1, h1f8, N, H, 2);

    // layer 2: t2 = ĥ1[i] + Σ ĥ1[src]; ĥ2 = di*(relu(di*(t2 W2)+b2) + ĥ1/di)
    aggregate256<<<agg_grid, 256, 0, stream>>>(h1f8, row_ptr, csr, tA, N, N);
    wgemm<256, 1, 1, 0, 1, 1><<<dim3(2, mtiles), 256, 0, stream>>>(tA, Wt2, b2, hh1, dinv, hh2, h2f8, N, H, 2);

    // layer 3: t3 = ĥ2[i] + Σ ĥ2[src]; h3 = relu(di*(t3 W3)+b3) + ĥ2/di
    aggregate256<<<agg_grid, 256, 0, stream>>>(h2f8, row_ptr, csr, tA, N, N);
    wgemm<256, 1, 1, 0, 2, 0><<<dim3(2, mtiles), 256, 0, stream>>>(tA, Wt3, b3, hh2, dinv, h3, nullptr, N, H, 2);

    // --- pool + MLP + LN -----------------------------------------------------
    pool_kernel<<<(G + 3) / 4, 256, 0, stream>>>(h3, batch, g0b, N, G);
    wgemm<256, 1, 0, 0, 0, 0><<<dim3(4, G / 128), 256, 0, stream>>>(g0b, Pt1, pb1, nullptr, nullptr, g1b, nullptr, G, H, 1);
    wgemm<256, 0, 0, 1, 0, 0><<<dim3(12, G / 128), 256, 0, stream>>>(g1b, Pt2, pb2, nullptr, nullptr, g2, nullptr, G, D, 1);
    ln_kernel<<<G / 4, 256, 0, stream>>>(g2, ln_g, ln_b, out, G);
}

// Round 7
// 343.435 us; speedup vs baseline: 1.0702x; 1.0439x over previous
//
#include <hip/hip_runtime.h>

// ---------------------------------------------------------------------------
// GraphEncoder round 21: three independent micro-fixes on the R20 best.
//  (1) aggregates: __launch_bounds__(256,8) caps VGPR at 64 (8 waves/SIMD) --
//      guards the 64-reg occupancy cliff the live-state estimate straddles.
//  (2) convert_all weight transpose: inverted mapping -> coalesced 2B writes,
//      strided 4B reads (L2 line reuse), pow2 shifts instead of div.
//  (3) pool: 4x unrolled independent row loads (4x MLP) + all-lane binary
//      search (no lane0 serialization).
// wgemm unchanged (R18 swizzled B + NT=2, measured best).
// ---------------------------------------------------------------------------

typedef __attribute__((ext_vector_type(8))) short short8;
typedef __attribute__((ext_vector_type(4))) float f32x4;
typedef __attribute__((ext_vector_type(2))) float f32x2;

__device__ __forceinline__ float bf2f(unsigned short s) {
    union { unsigned u; float f; } v;
    v.u = ((unsigned)s) << 16;
    return v.f;
}
__device__ __forceinline__ unsigned short f2bf(float f) {
    union { float f; unsigned u; } v;
    v.f = f;
    unsigned r = (v.u + 0x7FFFu + ((v.u >> 16) & 1u)) >> 16;
    return (unsigned short)r;
}
__device__ __forceinline__ unsigned pk2bf(float lo, float hi) {
    return (unsigned)f2bf(lo) | ((unsigned)f2bf(hi) << 16);
}
__device__ __forceinline__ unsigned short u4c(ushort4 v, int p) {
    return p == 0 ? v.x : p == 1 ? v.y : p == 2 ? v.z : v.w;
}

// accumulate 8 fp8 values (two packed dwords) into acc2[0..4) (f32x2 lanes)
__device__ __forceinline__ void acc8_fp8(unsigned int lo, unsigned int hi, f32x2* acc2) {
    acc2[0] += __builtin_amdgcn_cvt_pk_f32_fp8(lo, false);
    acc2[1] += __builtin_amdgcn_cvt_pk_f32_fp8(lo, true);
    acc2[2] += __builtin_amdgcn_cvt_pk_f32_fp8(hi, false);
    acc2[3] += __builtin_amdgcn_cvt_pk_f32_fp8(hi, true);
}

// ---------------------------- CSR build ------------------------------------

__global__ void count_kernel(const int* __restrict__ dst, int E, int* __restrict__ cnt,
                             int* __restrict__ rank) {
    int e = blockIdx.x * blockDim.x + threadIdx.x;
    if (e < E) rank[e] = atomicAdd(&cnt[dst[e]], 1);
}

__global__ void scanA(const int* __restrict__ cnt, int n, int* __restrict__ bsum,
                      float* __restrict__ dinv) {
    int tid = threadIdx.x, lane = tid & 63, w = tid >> 6;
    int i = blockIdx.x * 512 + tid;
    int v = (i < n) ? cnt[i] : 0;
    if (i < n) dinv[i] = rsqrtf((float)v + 1.0f);
    int s = v;
    #pragma unroll
    for (int off = 1; off < 64; off <<= 1) s += __shfl_xor(s, off);
    __shared__ int ws[8];
    if (lane == 0) ws[w] = s;
    __syncthreads();
    if (tid == 0) {
        int t = 0;
        #pragma unroll
        for (int j = 0; j < 8; j++) t += ws[j];
        bsum[blockIdx.x] = t;
    }
}

__global__ void scanC(const int* __restrict__ cnt, int n, const int* __restrict__ bsum,
                      int E, int* __restrict__ row_ptr) {
    int tid = threadIdx.x, lane = tid & 63, w = tid >> 6;
    int i = blockIdx.x * 512 + tid;
    __shared__ int s_boff;
    if (tid < 64) {
        int acc = 0;
        for (int b = tid; b < blockIdx.x; b += 64) acc += bsum[b];
        #pragma unroll
        for (int off = 1; off < 64; off <<= 1) acc += __shfl_xor(acc, off);
        if (tid == 0) s_boff = acc;
    }
    int v = (i < n) ? cnt[i] : 0;
    int incl = v;
    #pragma unroll
    for (int off = 1; off < 64; off <<= 1) {
        int t = __shfl_up(incl, off);
        if (lane >= off) incl += t;
    }
    __shared__ int ws[8];
    if (lane == 63) ws[w] = incl;
    __syncthreads();
    int woff = 0;
    for (int j = 0; j < w; j++) woff += ws[j];
    if (i < n) row_ptr[i] = s_boff + woff + incl - v;
    if (blockIdx.x == 0 && tid == 0) row_ptr[n] = E;
}

// ---------------------------- fused scatter + conversions ------------------
// [0, E):           scatter csr[row_ptr[dst]+rank] = src
// [E, E+n4):        x̂ = dinv*x -> fp8 shadow
// [E+n4, E+n4+tot): weight transpose, OUTPUT-linear mapping: thread t writes
//                   O[t] (coalesced 2B), reads W[k*Nn+n] (strided, L2-reused)
// tail (640):       zero fp8 dummy rows

__global__ void convert_all(const int* __restrict__ src, const int* __restrict__ dst,
                            const int* __restrict__ row_ptr, const int* __restrict__ rank,
                            int* __restrict__ csr, int E,
                            const float* __restrict__ x, const float* __restrict__ dinv,
                            unsigned char* __restrict__ xf8, int n4,
                            const float* __restrict__ W1, const float* __restrict__ W2,
                            const float* __restrict__ W3, const float* __restrict__ P1,
                            const float* __restrict__ P2,
                            unsigned short* __restrict__ Wt1, unsigned short* __restrict__ Wt2,
                            unsigned short* __restrict__ Wt3, unsigned short* __restrict__ Pt1,
                            unsigned short* __restrict__ Pt2,
                            int F_IN, int H, int D,
                            unsigned char* __restrict__ zx,
                            unsigned char* __restrict__ z1,
                            unsigned char* __restrict__ z2) {
    int gidx = blockIdx.x * blockDim.x + threadIdx.x;
    if (gidx < E) {
        csr[row_ptr[dst[gidx]] + rank[gidx]] = src[gidx];
        return;
    }
    int idx = gidx - E;
    if (idx < n4) {
        float di = dinv[idx >> 5];
        float4 v = ((const float4*)x)[idx];
        unsigned int p = 0;
        p = __builtin_amdgcn_cvt_pk_fp8_f32(di * v.x, di * v.y, p, false);
        p = __builtin_amdgcn_cvt_pk_fp8_f32(di * v.z, di * v.w, p, true);
        ((unsigned int*)xf8)[idx] = p;
        return;
    }
    int t = idx - n4;
    int n1 = F_IN * H, n2 = H * H, n5 = H * D;
    const float* W; unsigned short* O; int Nn, kshift;
    if (t < n1)              { W = W1; O = Wt1; Nn = H; kshift = 7; }   // K=128
    else if ((t -= n1) < n2) { W = W2; O = Wt2; Nn = H; kshift = 8; }
    else if ((t -= n2) < n2) { W = W3; O = Wt3; Nn = H; kshift = 8; }
    else if ((t -= n2) < n2) { W = P1; O = Pt1; Nn = H; kshift = 8; }
    else if ((t -= n2) < n5) { W = P2; O = Pt2; Nn = D; kshift = 8; }
    else {
        t -= n5;
        if (t < 128) zx[t] = 0;
        else if (t < 384) z1[t - 128] = 0;
        else if (t < 640) z2[t - 384] = 0;
        return;
    }
    // O layout [Nn][K]; t is linear over O: n = t>>kshift, k = t&(K-1)
    int n = t >> kshift, k = t & ((1 << kshift) - 1);
    O[t] = f2bf(W[(size_t)k * Nn + n]);
}

// ---------------------------- aggregation (fp8 gathers) --------------------
// R20 shape; __launch_bounds__(256,8) caps VGPR at 64 -> 8 waves/SIMD max.

__launch_bounds__(256, 8)
__global__ void aggregate256(const unsigned char* __restrict__ hf8,
                             const int* __restrict__ row_ptr,
                             const int* __restrict__ csr,
                             unsigned short* __restrict__ out, int n, int zrow) {
    int node = blockIdx.x * 4 + (threadIdx.x >> 6);
    int lane = threadIdx.x & 63;
    if (node >= n) return;
    int half = lane >> 5;          // which edge of the pair
    int cl = lane & 31;            // 8-col chunk
    f32x2 acc2[4];
    #pragma unroll
    for (int c = 0; c < 4; c++) acc2[c] = (f32x2){0.f, 0.f};
    if (half == 0) {
        uint2 sv = *(const uint2*)(hf8 + ((unsigned)node * 256u + (unsigned)cl * 8u));
        acc8_fp8(sv.x, sv.y, acc2);
    }
    int beg = row_ptr[node], end = row_ptr[node + 1];
    for (int base = beg; base < end; base += 64) {
        int k = base + lane;
        int mi = (k < end) ? csr[k] : zrow;
        int cnt = min(64, end - base);
        for (int j = 0; j < cnt; j += 16) {
            unsigned off[8]; uint2 vv[8];
            #pragma unroll
            for (int u = 0; u < 8; u++)
                off[u] = (unsigned)__shfl(mi, j + 2 * u + half) * 256u + (unsigned)cl * 8u;
            #pragma unroll
            for (int u = 0; u < 8; u++) vv[u] = *(const uint2*)(hf8 + off[u]);
            #pragma unroll
            for (int u = 0; u < 8; u++) acc8_fp8(vv[u].x, vv[u].y, acc2);
        }
    }
    #pragma unroll
    for (int c = 0; c < 4; c++) {
        acc2[c][0] += __shfl_xor(acc2[c][0], 32);
        acc2[c][1] += __shfl_xor(acc2[c][1], 32);
    }
    if (half == 0) {
        short8 o;
        #pragma unroll
        for (int c = 0; c < 8; c++) o[c] = (short)f2bf(acc2[c >> 1][c & 1]);
        *(short8*)(out + (size_t)node * 256 + cl * 8) = o;
    }
}

__launch_bounds__(256, 8)
__global__ void aggregate128(const unsigned char* __restrict__ hf8,
                             const int* __restrict__ row_ptr,
                             const int* __restrict__ csr,
                             unsigned short* __restrict__ out, int n, int zrow) {
    int node = blockIdx.x * 4 + (threadIdx.x >> 6);
    int lane = threadIdx.x & 63;
    if (node >= n) return;
    int qtr = lane >> 4;           // which edge of the quad
    int cl = lane & 15;            // 8-col chunk
    f32x2 acc2[4];
    #pragma unroll
    for (int c = 0; c < 4; c++) acc2[c] = (f32x2){0.f, 0.f};
    if (qtr == 0) {
        uint2 sv = *(const uint2*)(hf8 + ((unsigned)node * 128u + (unsigned)cl * 8u));
        acc8_fp8(sv.x, sv.y, acc2);
    }
    int beg = row_ptr[node], end = row_ptr[node + 1];
    for (int base = beg; base < end; base += 64) {
        int k = base + lane;
        int mi = (k < end) ? csr[k] : zrow;
        int cnt = min(64, end - base);
        for (int j = 0; j < cnt; j += 32) {
            unsigned off[8]; uint2 vv[8];
            #pragma unroll
            for (int u = 0; u < 8; u++)
                off[u] = (unsigned)__shfl(mi, j + 4 * u + qtr) * 128u + (unsigned)cl * 8u;
            #pragma unroll
            for (int u = 0; u < 8; u++) vv[u] = *(const uint2*)(hf8 + off[u]);
            #pragma unroll
            for (int u = 0; u < 8; u++) acc8_fp8(vv[u].x, vv[u].y, acc2);
        }
    }
    #pragma unroll
    for (int c = 0; c < 4; c++) {
        acc2[c][0] += __shfl_xor(acc2[c][0], 16);
        acc2[c][1] += __shfl_xor(acc2[c][1], 16);
        acc2[c][0] += __shfl_xor(acc2[c][0], 32);
        acc2[c][1] += __shfl_xor(acc2[c][1], 32);
    }
    if (qtr == 0) {
        short8 o;
        #pragma unroll
        for (int c = 0; c < 8; c++) o[c] = (short)f2bf(acc2[c >> 1][c & 1]);
        *(short8*)(out + (size_t)node * 128 + cl * 8) = o;
    }
}

// ---------------------------- wgemm (R18, measured best) -------------------
// C = epi(A[M,K] @ Bt[N,K]^T). 256-thr blocks = 4 waves x 32 rows (128 rows).
// A frags in registers; per 64-col tile B staged to LDS with XOR-swizzled
// 16B chunk slots (slot = ch ^ (row&7); row stride = K shorts) ->
// conflict-free ds_read_b128 b-frags. Swapped-operand MFMA -> C^T frags;
// register-only butterfly transpose epilogue. ntiles=2: one A-frag load
// serves two 64-col tiles.
// SCALE: 0 plain; 1: v=relu(di*acc+b)[+res/di], store di*v; 2: ...store v.
// FP8O: also store v as fp8 shadow (gather copy for the next aggregate).

template<int K, int RELU, int RES, int OUTF32, int SCALE, int FP8O>
__launch_bounds__(256)
__global__ void wgemm(const unsigned short* __restrict__ A,
                      const unsigned short* __restrict__ Bt,
                      const float* __restrict__ bias,
                      const unsigned short* __restrict__ residual,
                      const float* __restrict__ dinv,
                      void* __restrict__ Cout,
                      unsigned char* __restrict__ f8out,
                      int M, int N, int ntiles) {
    constexpr int KK = K / 32;
    constexpr int CPR = K / 8;
    __shared__ __align__(16) unsigned short Bs[64 * K];

    int tid = threadIdx.x;
    int wave = tid >> 6, lane = tid & 63;
    int r = lane & 15, q = lane >> 4;
    int mr = blockIdx.y * 128 + wave * 32;
    int nbase = blockIdx.x * ntiles * 64;

    short8 a[2][KK];
    #pragma unroll
    for (int mi = 0; mi < 2; mi++) {
        int arow = mr + mi * 16 + r;
        bool aok = arow < M;
        const unsigned short* ap = A + (size_t)(aok ? arow : 0) * K;
        #pragma unroll
        for (int kk = 0; kk < KK; kk++) {
            short8 v = *(const short8*)(ap + kk * 32 + q * 8);
            if (!aok) v = (short8){0, 0, 0, 0, 0, 0, 0, 0};
            a[mi][kk] = v;
        }
    }

    for (int t = 0; t < ntiles; t++) {
        int n0 = nbase + t * 64;
        if (t > 0) __syncthreads();
        #pragma unroll
        for (int pass = 0; pass < 64 * CPR / 256; pass++) {
            int f = pass * 256 + tid;
            int row = f / CPR, ch = f % CPR;
            *(short8*)&Bs[row * K + (ch ^ (row & 7)) * 8] =
                *(const short8*)(Bt + (size_t)(n0 + row) * K + ch * 8);
        }
        __syncthreads();

        f32x4 acc[2][4];
        #pragma unroll
        for (int mi = 0; mi < 2; mi++)
            #pragma unroll
            for (int j = 0; j < 4; j++) acc[mi][j] = (f32x4){0.f, 0.f, 0.f, 0.f};

        #pragma unroll
        for (int kk = 0; kk < KK; kk++) {
            short8 b[4];
            #pragma unroll
            for (int j = 0; j < 4; j++)
                b[j] = *(short8*)&Bs[(j * 16 + r) * K + ((kk * 4 + q) ^ (r & 7)) * 8];
            #pragma unroll
            for (int mi = 0; mi < 2; mi++)
                #pragma unroll
                for (int j = 0; j < 4; j++)
                    acc[mi][j] = __builtin_amdgcn_mfma_f32_16x16x32_bf16(b[j], a[mi][kk], acc[mi][j], 0, 0, 0);
        }

        // --- epilogue (register-only) ---
        // lane(q,r), reg p of acc[mi][j]: C[m = mr+mi*16+r][n = n0+j*16+q*4+p]
        f32x4 bq[4];
        #pragma unroll
        for (int j = 0; j < 4; j++)
            bq[j] = *(const f32x4*)&bias[n0 + j * 16 + q * 4];

        #pragma unroll
        for (int mi = 0; mi < 2; mi++) {
            int m = mr + mi * 16 + r;
            bool ok = m < M;
            float di = 1.f, rdi = 1.f;
            if (SCALE) { di = dinv[ok ? m : 0]; if (RES) rdi = 1.f / di; }
            ushort4 rv[4];
            if (RES) {
                const unsigned short* rp = residual + (size_t)(ok ? m : 0) * N + n0 + q * 4;
                #pragma unroll
                for (int j = 0; j < 4; j++) rv[j] = *(const ushort4*)(rp + j * 16);
            }
            float u[4][4];
            #pragma unroll
            for (int j = 0; j < 4; j++)
                #pragma unroll
                for (int p = 0; p < 4; p++) {
                    float v = (SCALE ? di * acc[mi][j][p] : acc[mi][j][p]) + bq[j][p];
                    if (RELU) v = fmaxf(v, 0.f);
                    if (RES) v += bf2f(u4c(rv[j], p)) * rdi;
                    if (SCALE == 1) v *= di;
                    u[j][p] = v;
                }

            if (OUTF32) {
                float c4[4][4], tf[4][4];
                #pragma unroll
                for (int j = 0; j < 4; j++)
                    #pragma unroll
                    for (int d = 0; d < 4; d++) c4[j][d] = u[j][d];
                #pragma unroll
                for (int j = 0; j < 4; j++)
                    #pragma unroll
                    for (int d = 0; d < 4; d++) tf[j][d] = __shfl_xor(c4[j ^ 1][d], 16);
                #pragma unroll
                for (int j = 0; j < 4; j++)
                    #pragma unroll
                    for (int d = 0; d < 4; d++)
                        c4[j][d] = (((j ^ q) & 1) == 0) ? c4[j][d] : tf[j][d];
                #pragma unroll
                for (int j = 0; j < 4; j++)
                    #pragma unroll
                    for (int d = 0; d < 4; d++) tf[j][d] = __shfl_xor(c4[j ^ 2][d], 32);
                #pragma unroll
                for (int j = 0; j < 4; j++)
                    #pragma unroll
                    for (int d = 0; d < 4; d++)
                        c4[j][d] = (((j ^ q) & 2) == 0) ? c4[j][d] : tf[j][d];
                if (ok) {
                    float* cp = (float*)Cout + (size_t)m * N + n0 + q * 16;
                    #pragma unroll
                    for (int j = 0; j < 4; j++) *(f32x4*)&cp[j * 4] = *(f32x4*)&c4[j][0];
                }
            } else {
                unsigned db[4][2], tb[4][2];
                #pragma unroll
                for (int j = 0; j < 4; j++) {
                    db[j][0] = pk2bf(u[j][0], u[j][1]);
                    db[j][1] = pk2bf(u[j][2], u[j][3]);
                }
                #pragma unroll
                for (int j = 0; j < 4; j++)
                    #pragma unroll
                    for (int d = 0; d < 2; d++) tb[j][d] = __shfl_xor((int)db[j ^ 1][d], 16);
                #pragma unroll
                for (int j = 0; j < 4; j++)
                    #pragma unroll
                    for (int d = 0; d < 2; d++)
                        db[j][d] = (((j ^ q) & 1) == 0) ? db[j][d] : tb[j][d];
                #pragma unroll
                for (int j = 0; j < 4; j++)
                    #pragma unroll
                    for (int d = 0; d < 2; d++) tb[j][d] = __shfl_xor((int)db[j ^ 2][d], 32);
                #pragma unroll
                for (int j = 0; j < 4; j++)
                    #pragma unroll
                    for (int d = 0; d < 2; d++)
                        db[j][d] = (((j ^ q) & 2) == 0) ? db[j][d] : tb[j][d];
                if (ok) {
                    unsigned short* cp = (unsigned short*)Cout + (size_t)m * N + n0 + q * 16;
                    *(uint4*)cp = make_uint4(db[0][0], db[0][1], db[1][0], db[1][1]);
                    *(uint4*)(cp + 8) = make_uint4(db[2][0], db[2][1], db[3][0], db[3][1]);
                }
                if (FP8O) {
                    unsigned f8[4], t8[4];
                    #pragma unroll
                    for (int j = 0; j < 4; j++) {
                        unsigned p8 = 0;
                        p8 = __builtin_amdgcn_cvt_pk_fp8_f32(u[j][0], u[j][1], p8, false);
                        p8 = __builtin_amdgcn_cvt_pk_fp8_f32(u[j][2], u[j][3], p8, true);
                        f8[j] = p8;
                    }
                    #pragma unroll
                    for (int j = 0; j < 4; j++) t8[j] = __shfl_xor((int)f8[j ^ 1], 16);
                    #pragma unroll
                    for (int j = 0; j < 4; j++)
                        f8[j] = (((j ^ q) & 1) == 0) ? f8[j] : t8[j];
                    #pragma unroll
                    for (int j = 0; j < 4; j++) t8[j] = __shfl_xor((int)f8[j ^ 2], 32);
                    #pragma unroll
                    for (int j = 0; j < 4; j++)
                        f8[j] = (((j ^ q) & 2) == 0) ? f8[j] : t8[j];
                    if (ok) {
                        unsigned char* fp = f8out + (size_t)m * N + n0 + q * 16;
                        *(uint4*)fp = make_uint4(f8[0], f8[1], f8[2], f8[3]);
                    }
                }
            }
        }
    }
}

// ---------------------------- pool / LN ------------------------------------

__launch_bounds__(256)
__global__ void pool_kernel(const unsigned short* __restrict__ h, const int* __restrict__ batch,
                            unsigned short* __restrict__ g0, int n, int G) {
    int g = blockIdx.x * 4 + (threadIdx.x >> 6);
    int lane = threadIdx.x & 63;
    if (g >= G) return;
    // all-lane binary search (wave-uniform addresses broadcast from cache)
    int a = 0, b = n;
    while (a < b) { int m = (a + b) >> 1; if (batch[m] < g) a = m + 1; else b = m; }
    int lo = a;
    int a2 = a, b2 = n;
    while (a2 < b2) { int m = (a2 + b2) >> 1; if (batch[m] < g + 1) a2 = m + 1; else b2 = m; }
    int hi = a2;
    // 4x unrolled independent accumulation (4 rows in flight)
    float s[4][4];
    #pragma unroll
    for (int u = 0; u < 4; u++)
        #pragma unroll
        for (int c = 0; c < 4; c++) s[u][c] = 0.f;
    int i = lo;
    for (; i + 4 <= hi; i += 4) {
        ushort4 v[4];
        #pragma unroll
        for (int u = 0; u < 4; u++)
            v[u] = *(const ushort4*)(h + (size_t)(i + u) * 256 + lane * 4);
        #pragma unroll
        for (int u = 0; u < 4; u++) {
            s[u][0] += bf2f(v[u].x); s[u][1] += bf2f(v[u].y);
            s[u][2] += bf2f(v[u].z); s[u][3] += bf2f(v[u].w);
        }
    }
    for (; i < hi; i++) {
        ushort4 v = *(const ushort4*)(h + (size_t)i * 256 + lane * 4);
        s[0][0] += bf2f(v.x); s[0][1] += bf2f(v.y);
        s[0][2] += bf2f(v.z); s[0][3] += bf2f(v.w);
    }
    float a0 = s[0][0] + s[1][0] + s[2][0] + s[3][0];
    float a1 = s[0][1] + s[1][1] + s[2][1] + s[3][1];
    float a2f = s[0][2] + s[1][2] + s[2][2] + s[3][2];
    float a3 = s[0][3] + s[1][3] + s[2][3] + s[3][3];
    float inv = 1.0f / fmaxf((float)(hi - lo), 1.0f);
    ushort4 o;
    o.x = f2bf(a0 * inv); o.y = f2bf(a1 * inv); o.z = f2bf(a2f * inv); o.w = f2bf(a3 * inv);
    *(ushort4*)(g0 + (size_t)g * 256 + lane * 4) = o;
}

__launch_bounds__(256)
__global__ void ln_kernel(const float* __restrict__ g2, const float* __restrict__ gamma,
                          const float* __restrict__ beta, float* __restrict__ out, int rows) {
    int row = blockIdx.x * 4 + (threadIdx.x >> 6);
    int lane = threadIdx.x & 63;
    if (row >= rows) return;
    const float* r = g2 + (size_t)row * 768;
    float v[12];
    float s = 0.f, s2 = 0.f;
    #pragma unroll
    for (int j = 0; j < 12; j++) {
        v[j] = r[lane + 64 * j];
        s += v[j];
        s2 += v[j] * v[j];
    }
    #pragma unroll
    for (int off = 32; off > 0; off >>= 1) {
        s += __shfl_down(s, off);
        s2 += __shfl_down(s2, off);
    }
    s = __shfl(s, 0);
    s2 = __shfl(s2, 0);
    float mu = s * (1.0f / 768.0f);
    float var = s2 * (1.0f / 768.0f) - mu * mu;
    float inv = rsqrtf(var + 1e-5f);
    #pragma unroll
    for (int j = 0; j < 12; j++) {
        int c = lane + 64 * j;
        out[(size_t)row * 768 + c] = (v[j] - mu) * inv * gamma[c] + beta[c];
    }
}

// ---------------------------------------------------------------------------

extern "C" void kernel_launch(void* const* d_in, const int* in_sizes, int n_in,
                              void* d_out, int out_size, void* d_ws, size_t ws_size,
                              hipStream_t stream) {
    const float* x    = (const float*)d_in[0];
    const int* eidx   = (const int*)d_in[1];
    const int* batch  = (const int*)d_in[2];
    const float* W1   = (const float*)d_in[3];
    const float* b1   = (const float*)d_in[4];
    const float* W2   = (const float*)d_in[5];
    const float* b2   = (const float*)d_in[6];
    const float* W3   = (const float*)d_in[7];
    const float* b3   = (const float*)d_in[8];
    const float* P1   = (const float*)d_in[9];
    const float* pb1  = (const float*)d_in[10];
    const float* P2   = (const float*)d_in[11];
    const float* pb2  = (const float*)d_in[12];
    const float* ln_g = (const float*)d_in[13];
    const float* ln_b = (const float*)d_in[14];
    float* out = (float*)d_out;

    const int N = in_sizes[2];            // 50000
    const int E = in_sizes[1] / 2;        // 800000
    const int F_IN = in_sizes[0] / N;     // 128
    const int H = in_sizes[4];            // 256
    const int D = in_sizes[12];           // 768
    const int G = out_size / D;           // 1024
    const int NPAD = (N + 127) & ~127;
    const int NB = (N + 511) / 512;       // scan blocks (<=128)

    const int* src = eidx;
    const int* dst = eidx + E;

    char* ws = (char*)d_ws;
    size_t off = 0;
    auto alloc = [&](size_t bytes) -> char* {
        char* p = ws + off;
        off = (off + bytes + 255) & ~(size_t)255;
        return p;
    };
    int*   cnt      = (int*)alloc((size_t)NPAD * 4);
    float* dinv     = (float*)alloc((size_t)NPAD * 4);
    int*   row_ptr  = (int*)alloc((size_t)(N + 1) * 4);
    int*   bsum     = (int*)alloc(128 * 4);
    int*   rank     = (int*)alloc((size_t)E * 4);
    int*   csr      = (int*)alloc((size_t)E * 4);
    unsigned char* xf8  = (unsigned char*)alloc((size_t)(N + 1) * F_IN);      // x̂ fp8, +dummy
    unsigned char* h1f8 = (unsigned char*)alloc((size_t)(N + 1) * H);         // ĥ1 fp8, +dummy
    unsigned char* h2f8 = (unsigned char*)alloc((size_t)(N + 1) * H);         // ĥ2 fp8, +dummy
    unsigned short* Wt1 = (unsigned short*)alloc((size_t)F_IN * H * 2);
    unsigned short* Wt2 = (unsigned short*)alloc((size_t)H * H * 2);
    unsigned short* Wt3 = (unsigned short*)alloc((size_t)H * H * 2);
    unsigned short* Pt1 = (unsigned short*)alloc((size_t)H * H * 2);
    unsigned short* Pt2 = (unsigned short*)alloc((size_t)H * D * 2);
    unsigned short* t1  = (unsigned short*)alloc((size_t)N * F_IN * 2);       // Σ x̂ (bf16)
    unsigned short* tA  = (unsigned short*)alloc((size_t)N * H * 2);          // Σ ĥ (bf16)
    unsigned short* hh1 = (unsigned short*)alloc((size_t)N * H * 2);          // ĥ1 bf16 (residual)
    unsigned short* hh2 = (unsigned short*)alloc((size_t)N * H * 2);          // ĥ2 bf16 (residual)
    unsigned short* h3  = (unsigned short*)alloc((size_t)N * H * 2);
    unsigned short* g0b = (unsigned short*)alloc((size_t)G * H * 2);
    unsigned short* g1b = (unsigned short*)alloc((size_t)G * H * 2);
    float* g2 = (float*)alloc((size_t)G * D * 4);
    (void)ws_size; (void)n_in;

    // --- CSR build -----------------------------------------------------------
    hipMemsetAsync(cnt, 0, (size_t)NPAD * 4, stream);
    count_kernel<<<(E + 255) / 256, 256, 0, stream>>>(dst, E, cnt, rank);
    scanA<<<NB, 512, 0, stream>>>(cnt, N, bsum, dinv);
    scanC<<<NB, 512, 0, stream>>>(cnt, N, bsum, E, row_ptr);

    // --- fused scatter + conversions (one launch) ---------------------------
    {
        int n4 = N * F_IN / 4;
        int tot = F_IN * H + 3 * H * H + H * D;
        int total = E + n4 + tot + 640;
        convert_all<<<(total + 255) / 256, 256, 0, stream>>>(
            src, dst, row_ptr, rank, csr, E,
            x, dinv, xf8, n4, W1, W2, W3, P1, P2, Wt1, Wt2, Wt3, Pt1, Pt2, F_IN, H, D,
            xf8 + (size_t)N * F_IN, h1f8 + (size_t)N * H, h2f8 + (size_t)N * H);
    }

    // --- GCN layers (aggregate-first, ĥ-space, fp8 gathers) -----------------
    int agg_grid = (N + 3) / 4;
    int mtiles = (N + 127) / 128;

    // layer 1: t1 = x̂[i] + Σ x̂[src]; ĥ1 = di*relu(di*(t1 W1) + b1)  (+fp8)
    aggregate128<<<agg_grid, 256, 0, stream>>>(xf8, row_ptr, csr, t1, N, N);
    wgemm<128, 1, 0, 0, 1, 1><<<dim3(2, mtiles), 256, 0, stream>>>(t1, Wt1, b1, nullptr, dinv, hh1, h1f8, N, H, 2);

    // layer 2: t2 = ĥ1[i] + Σ ĥ1[src]; ĥ2 = di*(relu(di*(t2 W2)+b2) + ĥ1/di)
    aggregate256<<<agg_grid, 256, 0, stream>>>(h1f8, row_ptr, csr, tA, N, N);
    wgemm<256, 1, 1, 0, 1, 1><<<dim3(2, mtiles), 256, 0, stream>>>(tA, Wt2, b2, hh1, dinv, hh2, h2f8, N, H, 2);

    // layer 3: t3 = ĥ2[i] + Σ ĥ2[src]; h3 = relu(di*(t3 W3)+b3) + ĥ2/di
    aggregate256<<<agg_grid, 256, 0, stream>>>(h2f8, row_ptr, csr, tA, N, N);
    wgemm<256, 1, 1, 0, 2, 0><<<dim3(2, mtiles), 256, 0, stream>>>(tA, Wt3, b3, hh2, dinv, h3, nullptr, N, H, 2);

    // --- pool + MLP + LN -----------------------------------------------------
    pool_kernel<<<(G + 3) / 4, 256, 0, stream>>>(h3, batch, g0b, N, G);
    wgemm<256, 1, 0, 0, 0, 0><<<dim3(4, G / 128), 256, 0, stream>>>(g0b, Pt1, pb1, nullptr, nullptr, g1b, nullptr, G, H, 1);
    wgemm<256, 0, 0, 1, 0, 0><<<dim3(12, G / 128), 256, 0, stream>>>(g1b, Pt2, pb2, nullptr, nullptr, g2, nullptr, G, D, 1);
    ln_kernel<<<G / 4, 256, 0, stream>>>(g2, ln_g, ln_b, out, G);
}